// Round 8
// baseline (1429.101 us; speedup 1.0000x reference)
//
#include <hip/hip_runtime.h>
#include <hip/hip_bf16.h>

#define DDIM 1024
#define HDIM 4096
#define NEXP 8
#define NROW 8192
#define KPAIR 8192   // 2 experts * HDIM

typedef __attribute__((ext_vector_type(8))) short s16x8;
typedef __attribute__((ext_vector_type(4))) float f32x4;

using bf16 = __hip_bfloat16;

// ---------------------------------------------------------------- helpers
__device__ __forceinline__ void gload16(const bf16* g, bf16* lds) {
    __builtin_amdgcn_global_load_lds(
        (const __attribute__((address_space(1))) unsigned int*)g,
        (__attribute__((address_space(3))) unsigned int*)lds,
        16, 0, 0);
}

template <int N>
__device__ __forceinline__ void wait_vmcnt() {
    if constexpr (N == 6)      asm volatile("s_waitcnt vmcnt(6)" ::: "memory");
    else if constexpr (N == 3) asm volatile("s_waitcnt vmcnt(3)" ::: "memory");
    else                       asm volatile("s_waitcnt vmcnt(0)" ::: "memory");
}

// ---------------------------------------------------------------- x -> bf16
__global__ void cvt_x_kernel(const float* __restrict__ x, bf16* __restrict__ xb, int total4) {
    int i = blockIdx.x * 256 + threadIdx.x;
    if (i >= total4) return;
    float4 v = ((const float4*)x)[i];
    union { bf16 b[4]; uint2 u; } p;
    p.b[0] = __float2bfloat16(v.x);
    p.b[1] = __float2bfloat16(v.y);
    p.b[2] = __float2bfloat16(v.z);
    p.b[3] = __float2bfloat16(v.w);
    ((uint2*)xb)[i] = p.u;
}

// ------------------ fp32 src [R][C] (+z*szs) -> bf16 dst [C][ldo] (+z*dzo)
// 64 src-rows x 128 src-cols per block, 256 threads. float4 reads, LDS
// re-layout [col][row] (pad 65: writes 4-way=cheap, reads 2-way=free),
// s16x8 stores: each inst covers 8 out-rows x 128B full lines.
__global__ void transpose_cvt_kernel(const float* __restrict__ src, bf16* __restrict__ dst,
                                     int R, int C, int ldo, size_t szs, int dzo) {
    __shared__ float t[128][65];
    const float* s = src + (size_t)blockIdx.z * szs;
    bf16* d = dst + (size_t)blockIdx.z * dzo;
    const int r0 = blockIdx.y * 64, c0 = blockIdx.x * 128;
    const int tid = threadIdx.x;
    const int lrow = tid >> 5, lc4 = tid & 31;
#pragma unroll
    for (int i = 0; i < 8; ++i) {
        int rr = i * 8 + lrow;
        float4 v = *(const float4*)&s[(size_t)(r0 + rr) * C + c0 + lc4 * 4];
        t[lc4 * 4 + 0][rr] = v.x;
        t[lc4 * 4 + 1][rr] = v.y;
        t[lc4 * 4 + 2][rr] = v.z;
        t[lc4 * 4 + 3][rr] = v.w;
    }
    __syncthreads();
    const int oc = tid >> 3, oj = tid & 7;
#pragma unroll
    for (int i = 0; i < 4; ++i) {
        int c = oc + i * 32;
        union { bf16 b[8]; s16x8 v; } p;
#pragma unroll
        for (int q = 0; q < 8; ++q) p.b[q] = __float2bfloat16(t[c][oj * 8 + q]);
        *(s16x8*)&d[(size_t)(c0 + c) * ldo + r0 + oj * 8] = p.v;
    }
}

// ---------------------------------------------------------------- gate softmax
__global__ void gate_kernel(const float* __restrict__ x, const float* __restrict__ Wg,
                            const float* __restrict__ bg, float* __restrict__ wts) {
    int wave = threadIdx.x >> 6, lane = threadIdx.x & 63;
    int n = blockIdx.x * 4 + wave;
    const float* xr = x + (size_t)n * DDIM;
    float acc[NEXP] = {0.f, 0.f, 0.f, 0.f, 0.f, 0.f, 0.f, 0.f};
    for (int d = lane; d < DDIM; d += 64) {
        float xv = xr[d];
        const float* wr = Wg + (size_t)d * NEXP;
#pragma unroll
        for (int e = 0; e < NEXP; ++e) acc[e] += xv * wr[e];
    }
#pragma unroll
    for (int off = 32; off > 0; off >>= 1) {
#pragma unroll
        for (int e = 0; e < NEXP; ++e) acc[e] += __shfl_xor(acc[e], off, 64);
    }
    if (lane == 0) {
        float mx = -1e30f;
#pragma unroll
        for (int e = 0; e < NEXP; ++e) { acc[e] += bg[e]; mx = fmaxf(mx, acc[e]); }
        float s = 0.f;
#pragma unroll
        for (int e = 0; e < NEXP; ++e) { acc[e] = __expf(acc[e] - mx); s += acc[e]; }
        float inv = 1.0f / s;
#pragma unroll
        for (int e = 0; e < NEXP; ++e) wts[(size_t)n * NEXP + e] = acc[e] * inv;
    }
}

// ------------------------------------------- out[n,d] = sum_e w[n,e]*b2[e,d]
__global__ void out_init_kernel(const float* __restrict__ wts, const float* __restrict__ b2,
                                float* __restrict__ out) {
    size_t idx = (size_t)blockIdx.x * 256 + threadIdx.x;
    int d = (int)(idx & (DDIM - 1));
    size_t n = idx >> 10;
    const float* w = wts + n * NEXP;
    float s = 0.f;
#pragma unroll
    for (int e = 0; e < NEXP; ++e) s += w[e] * b2[(size_t)e * DDIM + d];
    out[idx] = s;
}

// ---------------------------------------------------------------- out += Osc
__global__ void combine_kernel(float* __restrict__ out, const float* __restrict__ osc) {
    size_t i = (size_t)blockIdx.x * 256 + threadIdx.x;
    float4 a = ((const float4*)out)[i];
    float4 b = ((const float4*)osc)[i];
    a.x += b.x; a.y += b.y; a.z += b.z; a.w += b.w;
    ((float4*)out)[i] = a;
}

// ---------------------------------------------------------------- GEMM (8-phase, BK=64, BM=BN=256)
// Proven gemm1 structure (round 6/7: 5.3 TF/CU/block): 8 waves 2(M)x4(N),
// wave-tile 128x64, dbuf-2 LDS (128 KiB), 8 phases per 2 K-tiles, one
// half-matrix staged per phase, vmcnt(6) at ph4/ph8 only.
// Swizzle (0-conflict): 16B slot = kg ^ ((R>>1)&3), inverse on global src.
// MODE 1: Hs = wts[row,e]*relu(acc + b1[col]) -> bf16, LDS-buffered
//         coalesced store (round-6: kills write amplification).
// MODE 2: grid K-split x2 (virtual tn in [0,8): kh=tn>>2). kh=0 blocks do
//         out += acc (plain RMW); kh=1 blocks accumulate into Osc
//         (store if first pair else +=). No atomics, no races.
template <int MODE>
__global__ __launch_bounds__(512, 1) void gemm256(
    const bf16* __restrict__ A, const bf16* __restrict__ BT, void* __restrict__ Cout,
    float* __restrict__ Oalt, const float* __restrict__ bias, const float* __restrict__ wts,
    int lda, int ldb, int ldc, int NT, int tilesM, int tilesN, int XGN,
    int expert, int first) {
    constexpr int WROWS = 128;
    constexpr int HALFA = 256 * 32;
    constexpr int HALFB = 256 * 32;
    constexpr int ATOT = 2 * HALFA;
    constexpr int BUFE = ATOT + 2 * HALFB;  // 32768 elems
    __shared__ __align__(16) bf16 smem[2 * BUFE];

    const int tid = threadIdx.x;
    const int wave = tid >> 6, lane = tid & 63;
    const int wm = wave >> 2, wn = wave & 3;
    const int r = lane & 15, kg = lane >> 4;

    // ---- 2-D XCD-aware tile mapping (round-3 FETCH-verified)
    const int xcd = blockIdx.x & 7, slot = blockIdx.x >> 3;
    const int XGM = 8 / XGN;
    const int rm = tilesM / XGM, rn = tilesN / XGN;
    const int g = slot >> 5, u = slot & 31;
    const int gpr = rn >> 3;
    const int gm = (g / gpr) * 4 + (u >> 3);
    const int gn = (g % gpr) * 8 + (u & 7);
    const int tm = (xcd / XGN) * rm + gm;
    const int tn_v = (xcd % XGN) * rn + gn;

    int kh = 0, tn = tn_v;
    if constexpr (MODE == 2) { kh = tn_v >> 2; tn = tn_v & 3; }
    const int kofs = kh * NT * 64;

    const bf16* gA = A + (size_t)tm * 256 * lda + kofs;
    const bf16* gB = BT + (size_t)tn * 256 * ldb + kofs;

    f32x4 acc[8][4];
#pragma unroll
    for (int m = 0; m < 8; ++m)
#pragma unroll
        for (int n = 0; n < 4; ++n) acc[m][n] = (f32x4){0.f, 0.f, 0.f, 0.f};

    auto stageA = [&](int t, int ks) {
        bf16* dst = smem + (t & 1) * BUFE + ks * HALFA;
#pragma unroll
        for (int j = 0; j < 2; ++j) {
            int c = j * 512 + tid;
            int R = c >> 2, kc = (c & 3) ^ ((R >> 1) & 3);
            gload16(gA + (size_t)R * lda + t * 64 + ks * 32 + kc * 8,
                    dst + (j * 512 + wave * 64) * 8);
        }
    };
    auto stageB = [&](int t, int ks) {
        bf16* dst = smem + (t & 1) * BUFE + ATOT + ks * HALFB;
#pragma unroll
        for (int j = 0; j < 2; ++j) {
            int c = j * 512 + tid;
            int R = c >> 2, kc = (c & 3) ^ ((R >> 1) & 3);
            gload16(gB + (size_t)R * ldb + t * 64 + ks * 32 + kc * 8,
                    dst + (j * 512 + wave * 64) * 8);
        }
    };

    s16x8 a0[4], bb[4];
    auto ldA = [&](int buf, int ks, int mh) {
#pragma unroll
        for (int m = 0; m < 4; ++m) {
            int R = wm * WROWS + mh * 64 + m * 16 + r;
            a0[m] = *(const s16x8*)&smem[buf * BUFE + ks * HALFA + R * 32 +
                                         ((kg ^ ((R >> 1) & 3)) * 8)];
        }
    };
    auto ldB = [&](int buf, int ks) {
#pragma unroll
        for (int n = 0; n < 4; ++n) {
            int R = wn * 64 + n * 16 + r;
            bb[n] = *(const s16x8*)&smem[buf * BUFE + ATOT + ks * HALFB + R * 32 +
                                         ((kg ^ ((R >> 1) & 3)) * 8)];
        }
    };

    auto preMFMA = [&]() {
        __builtin_amdgcn_s_barrier();
        asm volatile("s_waitcnt lgkmcnt(0)" ::: "memory");
        __builtin_amdgcn_sched_barrier(0);
        __builtin_amdgcn_s_setprio(1);
    };
    auto postMFMA = [&](bool vm) {
        __builtin_amdgcn_s_setprio(0);
        if (vm) wait_vmcnt<6>();
        __builtin_amdgcn_s_barrier();
    };
    auto mfmaLo = [&]() {
#pragma unroll
        for (int m = 0; m < 4; ++m)
#pragma unroll
            for (int n = 0; n < 4; ++n)
                acc[m][n] = __builtin_amdgcn_mfma_f32_16x16x32_bf16(a0[m], bb[n], acc[m][n], 0, 0, 0);
    };
    auto mfmaHi = [&]() {
#pragma unroll
        for (int m = 0; m < 4; ++m)
#pragma unroll
            for (int n = 0; n < 4; ++n)
                acc[4 + m][n] = __builtin_amdgcn_mfma_f32_16x16x32_bf16(a0[m], bb[n], acc[4 + m][n], 0, 0, 0);
    };

    // prologue
    stageB(0, 0); stageA(0, 0); stageB(0, 1); stageA(0, 1);
    stageB(1, 0); stageA(1, 0); stageB(1, 1);   // A(1,1) staged at iter0 ph1
    wait_vmcnt<6>();
    __builtin_amdgcn_s_barrier();

    const int NI = NT / 2;
    for (int i = 0; i < NI; ++i) {
        const int t0 = 2 * i, t1 = t0 + 1;
        const bool g2 = (t0 + 2 < NT), g3 = (t1 + 2 < NT);
        ldB(0, 0); ldA(0, 0, 0); stageA(t1, 1);
        preMFMA(); mfmaLo(); postMFMA(false);
        ldA(0, 0, 1); if (g2) stageB(t0 + 2, 0);
        preMFMA(); mfmaHi(); postMFMA(false);
        ldB(0, 1); ldA(0, 1, 0); if (g2) stageA(t0 + 2, 0);
        preMFMA(); mfmaLo(); postMFMA(false);
        ldA(0, 1, 1); if (g2) stageB(t0 + 2, 1);
        preMFMA(); mfmaHi(); postMFMA(true);
        ldB(1, 0); ldA(1, 0, 0); if (g2) stageA(t0 + 2, 1);
        preMFMA(); mfmaLo(); postMFMA(false);
        ldA(1, 0, 1); if (g3) stageB(t1 + 2, 0);
        preMFMA(); mfmaHi(); postMFMA(false);
        ldB(1, 1); ldA(1, 1, 0); if (g3) stageA(t1 + 2, 0);
        preMFMA(); mfmaLo(); postMFMA(false);
        ldA(1, 1, 1); if (g3) stageB(t1 + 2, 1);
        preMFMA(); mfmaHi(); postMFMA(true);
    }

    // ---- epilogue. acc C/D: col = r, row = kg*4 + j within each 16x16 frag
    if constexpr (MODE == 1) {
        // Hs = w * relu(acc + bias), LDS-buffered coalesced store
        bf16* hs = smem;                         // 65536 elems == 256*256
        const int col0 = tn * 256 + wn * 64;
#pragma unroll
        for (int n = 0; n < 4; ++n) {
            float bv = bias[col0 + n * 16 + r];
            int cl = wn * 64 + n * 16 + r;
#pragma unroll
            for (int mf = 0; mf < 8; ++mf) {
#pragma unroll
                for (int j = 0; j < 4; ++j) {
                    int rl = wm * WROWS + (mf >> 2) * 64 + (mf & 3) * 16 + kg * 4 + j;
                    float wv = wts[((size_t)tm * 256 + rl) * NEXP + expert];
                    float v = acc[mf][n][j] + bv;
                    v = v > 0.f ? v : 0.f;
                    hs[rl * 256 + cl] = __float2bfloat16(wv * v);
                }
            }
        }
        __builtin_amdgcn_s_barrier();
        asm volatile("s_waitcnt lgkmcnt(0)" ::: "memory");
        bf16* H = (bf16*)Cout;
        const size_t rbase = (size_t)tm * 256;
        const int cbase = tn * 256;
#pragma unroll
        for (int i2 = 0; i2 < 16; ++i2) {
            int rl = wave * 32 + i2 * 2 + (lane >> 5);
            int c8 = (lane & 31) * 8;
            s16x8 v = *(const s16x8*)&hs[rl * 256 + c8];
            *(s16x8*)&H[(rbase + rl) * (size_t)ldc + cbase + c8] = v;
        }
    } else {
        float* O = (kh == 0) ? (float*)Cout : Oalt;
        const bool rmw = (kh == 0) || (first == 0);
        const size_t row0 = (size_t)tm * 256 + wm * WROWS;
        const int col0 = tn * 256 + wn * 64;
#pragma unroll
        for (int mf = 0; mf < 8; ++mf) {
#pragma unroll
            for (int j = 0; j < 4; ++j) {
                size_t rr = row0 + (mf >> 2) * 64 + (mf & 3) * 16 + kg * 4 + j;
#pragma unroll
                for (int n = 0; n < 4; ++n) {
                    size_t o = rr * (size_t)ldc + col0 + n * 16 + r;
                    if (rmw) O[o] += acc[mf][n][j];
                    else     O[o] = acc[mf][n][j];
                }
            }
        }
    }
}

// ---------------------------------------------------------------- launch
extern "C" void kernel_launch(void* const* d_in, const int* in_sizes, int n_in,
                              void* d_out, int out_size, void* d_ws, size_t ws_size,
                              hipStream_t stream) {
    const float* x  = (const float*)d_in[0];
    const float* Wg = (const float*)d_in[1];
    const float* bg = (const float*)d_in[2];
    const float* W1 = (const float*)d_in[3];
    const float* b1 = (const float*)d_in[4];
    const float* W2 = (const float*)d_in[5];
    const float* b2 = (const float*)d_in[6];
    float* out = (float*)d_out;

    char* ws = (char*)d_ws;
    bf16* xb   = (bf16*)(ws);                          // 16 MiB  [N][D]
    bf16* W1Te = (bf16*)(ws + (16ull << 20));          // 8 MiB   [H][D] (one expert)
    bf16* W2P  = (bf16*)(ws + (24ull << 20));          // 16 MiB  [D][KPAIR] (pair)
    bf16* Hs   = (bf16*)(ws + (40ull << 20));          // 128 MiB [N][KPAIR] (pair)
    float* Osc = (float*)(ws + (168ull << 20));        // 32 MiB  [N][D] kh=1 partials
    float* wts = (float*)(ws + (200ull << 20));        // 256 KiB [N][E]

    cvt_x_kernel<<<NROW * DDIM / 4 / 256, 256, 0, stream>>>(x, xb, NROW * DDIM / 4);
    gate_kernel<<<NROW / 4, 256, 0, stream>>>(x, Wg, bg, wts);
    out_init_kernel<<<NROW * DDIM / 256, 256, 0, stream>>>(wts, b2, out);

    for (int p = 0; p < 4; ++p) {
        for (int h = 0; h < 2; ++h) {
            int e = 2 * p + h;
            // W1[e]: [D][H] -> W1Te [H][D]
            transpose_cvt_kernel<<<dim3(HDIM / 128, DDIM / 64, 1), 256, 0, stream>>>(
                W1 + (size_t)e * DDIM * HDIM, W1Te, DDIM, HDIM, DDIM, 0, 0);
            // GEMM1: Hs[:, h*H ..] = w * relu(x @ W1[e] + b1[e])
            gemm256<1><<<512, 512, 0, stream>>>(
                xb, W1Te, Hs + (size_t)h * HDIM, nullptr, b1 + (size_t)e * HDIM, wts,
                DDIM, DDIM, KPAIR, DDIM / 64, 32, 16, 2, e, 0);
        }
        // W2 pair: [2][H][D] -> W2P [D][KPAIR]
        transpose_cvt_kernel<<<dim3(DDIM / 128, HDIM / 64, 2), 256, 0, stream>>>(
            W2 + (size_t)2 * p * HDIM * DDIM, W2P, HDIM, DDIM, KPAIR,
            (size_t)HDIM * DDIM, HDIM);
        // GEMM2: out/Osc accumulate Hs @ W2P^T (M=8192 N=1024 K=8192, Ksplit x2)
        gemm256<2><<<256, 512, 0, stream>>>(
            Hs, W2P, out, Osc, nullptr, nullptr,
            KPAIR, KPAIR, DDIM, 64, 32, 8, 1, 0, (p == 0) ? 1 : 0);
    }
    combine_kernel<<<NROW * DDIM / 4 / 256, 256, 0, stream>>>(out, Osc);
}

// Round 9
// 1341.854 us; speedup vs baseline: 1.0650x; 1.0650x over previous
//
#include <hip/hip_runtime.h>
#include <hip/hip_bf16.h>

#define DDIM 1024
#define HDIM 4096
#define NEXP 8
#define NROW 8192
#define KPAIR 8192   // 2 experts * HDIM

typedef __attribute__((ext_vector_type(8))) short s16x8;
typedef __attribute__((ext_vector_type(4))) float f32x4;

using bf16 = __hip_bfloat16;

// ---------------------------------------------------------------- helpers
__device__ __forceinline__ void gload16(const bf16* g, bf16* lds) {
    __builtin_amdgcn_global_load_lds(
        (const __attribute__((address_space(1))) unsigned int*)g,
        (__attribute__((address_space(3))) unsigned int*)lds,
        16, 0, 0);
}

template <int N>
__device__ __forceinline__ void wait_vmcnt() {
    if constexpr (N == 6)      asm volatile("s_waitcnt vmcnt(6)" ::: "memory");
    else if constexpr (N == 3) asm volatile("s_waitcnt vmcnt(3)" ::: "memory");
    else                       asm volatile("s_waitcnt vmcnt(0)" ::: "memory");
}

// ---------------------------------------------------------------- x -> bf16
__global__ void cvt_x_kernel(const float* __restrict__ x, bf16* __restrict__ xb, int total4) {
    int i = blockIdx.x * 256 + threadIdx.x;
    if (i >= total4) return;
    float4 v = ((const float4*)x)[i];
    union { bf16 b[4]; uint2 u; } p;
    p.b[0] = __float2bfloat16(v.x);
    p.b[1] = __float2bfloat16(v.y);
    p.b[2] = __float2bfloat16(v.z);
    p.b[3] = __float2bfloat16(v.w);
    ((uint2*)xb)[i] = p.u;
}

// ------------------ fp32 src [R][C] (+z*szs) -> bf16 dst [C][ldo] (+z*dzo)
// 64 src-rows x 128 src-cols per block, 256 threads. float4 reads, LDS
// re-layout, s16x8 stores = 8 out-elems of one out-row (full 128B lines).
// Round-8-verified correct & fast.
__global__ void transpose_cvt_kernel(const float* __restrict__ src, bf16* __restrict__ dst,
                                     int R, int C, int ldo, size_t szs, int dzo) {
    __shared__ float t[128][65];
    const float* s = src + (size_t)blockIdx.z * szs;
    bf16* d = dst + (size_t)blockIdx.z * dzo;
    const int r0 = blockIdx.y * 64, c0 = blockIdx.x * 128;
    const int tid = threadIdx.x;
    const int lrow = tid >> 5, lc4 = tid & 31;
#pragma unroll
    for (int i = 0; i < 8; ++i) {
        int rr = i * 8 + lrow;
        float4 v = *(const float4*)&s[(size_t)(r0 + rr) * C + c0 + lc4 * 4];
        t[lc4 * 4 + 0][rr] = v.x;
        t[lc4 * 4 + 1][rr] = v.y;
        t[lc4 * 4 + 2][rr] = v.z;
        t[lc4 * 4 + 3][rr] = v.w;
    }
    __syncthreads();
    const int oc = tid >> 3, oj = tid & 7;
#pragma unroll
    for (int i = 0; i < 4; ++i) {
        int c = oc + i * 32;
        union { bf16 b[8]; s16x8 v; } p;
#pragma unroll
        for (int q = 0; q < 8; ++q) p.b[q] = __float2bfloat16(t[c][oj * 8 + q]);
        *(s16x8*)&d[(size_t)(c0 + c) * ldo + r0 + oj * 8] = p.v;
    }
}

// ---------------------------------------------------------------- gate softmax
__global__ void gate_kernel(const float* __restrict__ x, const float* __restrict__ Wg,
                            const float* __restrict__ bg, float* __restrict__ wts) {
    int wave = threadIdx.x >> 6, lane = threadIdx.x & 63;
    int n = blockIdx.x * 4 + wave;
    const float* xr = x + (size_t)n * DDIM;
    float acc[NEXP] = {0.f, 0.f, 0.f, 0.f, 0.f, 0.f, 0.f, 0.f};
    for (int d = lane; d < DDIM; d += 64) {
        float xv = xr[d];
        const float* wr = Wg + (size_t)d * NEXP;
#pragma unroll
        for (int e = 0; e < NEXP; ++e) acc[e] += xv * wr[e];
    }
#pragma unroll
    for (int off = 32; off > 0; off >>= 1) {
#pragma unroll
        for (int e = 0; e < NEXP; ++e) acc[e] += __shfl_xor(acc[e], off, 64);
    }
    if (lane == 0) {
        float mx = -1e30f;
#pragma unroll
        for (int e = 0; e < NEXP; ++e) { acc[e] += bg[e]; mx = fmaxf(mx, acc[e]); }
        float s = 0.f;
#pragma unroll
        for (int e = 0; e < NEXP; ++e) { acc[e] = __expf(acc[e] - mx); s += acc[e]; }
        float inv = 1.0f / s;
#pragma unroll
        for (int e = 0; e < NEXP; ++e) wts[(size_t)n * NEXP + e] = acc[e] * inv;
    }
}

// ------------------------------------------- out[n,d] = sum_e w[n,e]*b2[e,d]
__global__ void out_init_kernel(const float* __restrict__ wts, const float* __restrict__ b2,
                                float* __restrict__ out) {
    size_t idx = (size_t)blockIdx.x * 256 + threadIdx.x;
    int d = (int)(idx & (DDIM - 1));
    size_t n = idx >> 10;
    const float* w = wts + n * NEXP;
    float s = 0.f;
#pragma unroll
    for (int e = 0; e < NEXP; ++e) s += w[e] * b2[(size_t)e * DDIM + d];
    out[idx] = s;
}

// ---------------------------------------------------------------- GEMM1 (8-phase, BK=64)
// BM=256 x BN=256, 8 waves 2(M)x4(N), wave-tile 128x64. Round-6/7-proven.
// Epilogue: Hs = wts[row,e] * relu(acc + b1[col]) -> bf16, LDS-buffered
// coalesced store.
__global__ __launch_bounds__(512, 1) void gemm1(
    const bf16* __restrict__ A, const bf16* __restrict__ BT, bf16* __restrict__ Cout,
    const float* __restrict__ bias, const float* __restrict__ wts,
    int lda, int ldb, int ldc, int NT, int tilesM, int tilesN, int XGN, int expert) {
    constexpr int WROWS = 128;
    constexpr int HALFA = 256 * 32;
    constexpr int HALFB = 256 * 32;
    constexpr int ATOT = 2 * HALFA;
    constexpr int BUFE = ATOT + 2 * HALFB;  // 32768 elems
    __shared__ __align__(16) bf16 smem[2 * BUFE];

    const int tid = threadIdx.x;
    const int wave = tid >> 6, lane = tid & 63;
    const int wm = wave >> 2, wn = wave & 3;
    const int r = lane & 15, kg = lane >> 4;

    // ---- 2-D XCD-aware tile mapping (round-3 FETCH-verified)
    const int xcd = blockIdx.x & 7, slot = blockIdx.x >> 3;
    const int XGM = 8 / XGN;
    const int rm = tilesM / XGM, rn = tilesN / XGN;
    const int g = slot >> 5, u = slot & 31;
    const int gpr = rn >> 3;
    const int gm = (g / gpr) * 4 + (u >> 3);
    const int gn = (g % gpr) * 8 + (u & 7);
    const int tm = (xcd / XGN) * rm + gm;
    const int tn = (xcd % XGN) * rn + gn;

    const bf16* gA = A + (size_t)tm * 256 * lda;
    const bf16* gB = BT + (size_t)tn * 256 * ldb;

    f32x4 acc[8][4];
#pragma unroll
    for (int m = 0; m < 8; ++m)
#pragma unroll
        for (int n = 0; n < 4; ++n) acc[m][n] = (f32x4){0.f, 0.f, 0.f, 0.f};

    auto stageA = [&](int t, int ks) {
        bf16* dst = smem + (t & 1) * BUFE + ks * HALFA;
#pragma unroll
        for (int j = 0; j < 2; ++j) {
            int c = j * 512 + tid;
            int R = c >> 2, kc = (c & 3) ^ ((R >> 1) & 3);
            gload16(gA + (size_t)R * lda + t * 64 + ks * 32 + kc * 8,
                    dst + (j * 512 + wave * 64) * 8);
        }
    };
    auto stageB = [&](int t, int ks) {
        bf16* dst = smem + (t & 1) * BUFE + ATOT + ks * HALFB;
#pragma unroll
        for (int j = 0; j < 2; ++j) {
            int c = j * 512 + tid;
            int R = c >> 2, kc = (c & 3) ^ ((R >> 1) & 3);
            gload16(gB + (size_t)R * ldb + t * 64 + ks * 32 + kc * 8,
                    dst + (j * 512 + wave * 64) * 8);
        }
    };

    s16x8 a0[4], bb[4];
    auto ldA = [&](int buf, int ks, int mh) {
#pragma unroll
        for (int m = 0; m < 4; ++m) {
            int R = wm * WROWS + mh * 64 + m * 16 + r;
            a0[m] = *(const s16x8*)&smem[buf * BUFE + ks * HALFA + R * 32 +
                                         ((kg ^ ((R >> 1) & 3)) * 8)];
        }
    };
    auto ldB = [&](int buf, int ks) {
#pragma unroll
        for (int n = 0; n < 4; ++n) {
            int R = wn * 64 + n * 16 + r;
            bb[n] = *(const s16x8*)&smem[buf * BUFE + ATOT + ks * HALFB + R * 32 +
                                         ((kg ^ ((R >> 1) & 3)) * 8)];
        }
    };

    auto preMFMA = [&]() {
        __builtin_amdgcn_s_barrier();
        asm volatile("s_waitcnt lgkmcnt(0)" ::: "memory");
        __builtin_amdgcn_sched_barrier(0);
        __builtin_amdgcn_s_setprio(1);
    };
    auto postMFMA = [&](bool vm) {
        __builtin_amdgcn_s_setprio(0);
        if (vm) wait_vmcnt<6>();
        __builtin_amdgcn_s_barrier();
    };
    auto mfmaLo = [&]() {
#pragma unroll
        for (int m = 0; m < 4; ++m)
#pragma unroll
            for (int n = 0; n < 4; ++n)
                acc[m][n] = __builtin_amdgcn_mfma_f32_16x16x32_bf16(a0[m], bb[n], acc[m][n], 0, 0, 0);
    };
    auto mfmaHi = [&]() {
#pragma unroll
        for (int m = 0; m < 4; ++m)
#pragma unroll
            for (int n = 0; n < 4; ++n)
                acc[4 + m][n] = __builtin_amdgcn_mfma_f32_16x16x32_bf16(a0[m], bb[n], acc[4 + m][n], 0, 0, 0);
    };

    // prologue
    stageB(0, 0); stageA(0, 0); stageB(0, 1); stageA(0, 1);
    stageB(1, 0); stageA(1, 0); stageB(1, 1);   // A(1,1) staged at iter0 ph1
    wait_vmcnt<6>();
    __builtin_amdgcn_s_barrier();

    const int NI = NT / 2;
    for (int i = 0; i < NI; ++i) {
        const int t0 = 2 * i, t1 = t0 + 1;
        const bool g2 = (t0 + 2 < NT), g3 = (t1 + 2 < NT);
        ldB(0, 0); ldA(0, 0, 0); stageA(t1, 1);
        preMFMA(); mfmaLo(); postMFMA(false);
        ldA(0, 0, 1); if (g2) stageB(t0 + 2, 0);
        preMFMA(); mfmaHi(); postMFMA(false);
        ldB(0, 1); ldA(0, 1, 0); if (g2) stageA(t0 + 2, 0);
        preMFMA(); mfmaLo(); postMFMA(false);
        ldA(0, 1, 1); if (g2) stageB(t0 + 2, 1);
        preMFMA(); mfmaHi(); postMFMA(true);
        ldB(1, 0); ldA(1, 0, 0); if (g2) stageA(t0 + 2, 1);
        preMFMA(); mfmaLo(); postMFMA(false);
        ldA(1, 0, 1); if (g3) stageB(t1 + 2, 0);
        preMFMA(); mfmaHi(); postMFMA(false);
        ldB(1, 1); ldA(1, 1, 0); if (g3) stageA(t1 + 2, 0);
        preMFMA(); mfmaLo(); postMFMA(false);
        ldA(1, 1, 1); if (g3) stageB(t1 + 2, 1);
        preMFMA(); mfmaHi(); postMFMA(true);
    }

    // ---- epilogue: Hs = w * relu(acc + bias), LDS-buffered coalesced store
    bf16* hs = smem;                         // 65536 elems == 256*256
    const int col0 = tn * 256 + wn * 64;
#pragma unroll
    for (int n = 0; n < 4; ++n) {
        float bv = bias[col0 + n * 16 + r];
        int cl = wn * 64 + n * 16 + r;
#pragma unroll
        for (int mf = 0; mf < 8; ++mf) {
#pragma unroll
            for (int j = 0; j < 4; ++j) {
                int rl = wm * WROWS + (mf >> 2) * 64 + (mf & 3) * 16 + kg * 4 + j;
                float wv = wts[((size_t)tm * 256 + rl) * NEXP + expert];
                float v = acc[mf][n][j] + bv;
                v = v > 0.f ? v : 0.f;
                hs[rl * 256 + cl] = __float2bfloat16(wv * v);
            }
        }
    }
    __builtin_amdgcn_s_barrier();
    asm volatile("s_waitcnt lgkmcnt(0)" ::: "memory");
    const size_t rbase = (size_t)tm * 256;
    const int cbase = tn * 256;
#pragma unroll
    for (int i2 = 0; i2 < 16; ++i2) {
        int rl = wave * 32 + i2 * 2 + (lane >> 5);
        int c8 = (lane & 31) * 8;
        s16x8 v = *(const s16x8*)&hs[rl * 256 + c8];
        *(s16x8*)&Cout[(rbase + rl) * (size_t)ldc + cbase + c8] = v;
    }
}

// ---------------------------------------------------------------- GEMM2 (expert-pair, K=8192)
// BM=256 x BN=128, BK=64, ring-3 LDS (144 KiB). 8 waves = 2(M)x2(N)x2(Ksw):
// wave-tile 128x64 over one 32-k half -> 12 ds_reads / 32 MFMA (0.375).
// Cross-ksw reduce via LDS with stride-68 pad (2-way banks = free;
// round-7's stride-64 had 524K conflict cycles), then fp32 RMW into out.
__global__ __launch_bounds__(512, 1) void gemm2pair(
    const bf16* __restrict__ A, const bf16* __restrict__ BT, float* __restrict__ O,
    int lda, int ldb, int ldc, int NT, int tilesM, int tilesN, int XGN) {
    constexpr int HALFA = 256 * 32;          // 8192 elems
    constexpr int HALFB = 128 * 32;          // 4096 elems
    constexpr int ATOT = 2 * HALFA;
    constexpr int BUFE = ATOT + 2 * HALFB;   // 24576 elems
    constexpr int RSTR = 68;                 // padded reduce stride (f32)
    __shared__ __align__(16) bf16 smem[3 * BUFE];   // 144 KiB

    const int tid = threadIdx.x;
    const int wave = tid >> 6, lane = tid & 63;
    const int ksw = wave & 1, wn = (wave >> 1) & 1, wm = wave >> 2;
    const int r = lane & 15, kg = lane >> 4;

    // ---- 2-D XCD-aware tile mapping (round-3 FETCH-verified)
    const int xcd = blockIdx.x & 7, slot = blockIdx.x >> 3;
    const int XGM = 8 / XGN;
    const int rm = tilesM / XGM, rn = tilesN / XGN;
    const int g = slot >> 5, u = slot & 31;
    const int gpr = rn >> 3;
    const int gm = (g / gpr) * 4 + (u >> 3);
    const int gn = (g % gpr) * 8 + (u & 7);
    const int tm = (xcd / XGN) * rm + gm;
    const int tn = (xcd % XGN) * rn + gn;

    const bf16* gA = A + (size_t)tm * 256 * lda;
    const bf16* gB = BT + (size_t)tn * 128 * ldb;

    f32x4 acc[8][4];
#pragma unroll
    for (int m = 0; m < 8; ++m)
#pragma unroll
        for (int n = 0; n < 4; ++n) acc[m][n] = (f32x4){0.f, 0.f, 0.f, 0.f};

    auto stageA = [&](int t, int ks) {
        bf16* dst = smem + (t % 3) * BUFE + ks * HALFA;
#pragma unroll
        for (int j = 0; j < 2; ++j) {
            int c = j * 512 + tid;
            int R = c >> 2, kc = (c & 3) ^ ((R >> 1) & 3);
            gload16(gA + (size_t)R * lda + t * 64 + ks * 32 + kc * 8,
                    dst + (j * 512 + wave * 64) * 8);
        }
    };
    auto stageB = [&](int t, int ks) {
        bf16* dst = smem + (t % 3) * BUFE + ATOT + ks * HALFB;
        int R = tid >> 2, kc = (tid & 3) ^ ((R >> 1) & 3);
        gload16(gB + (size_t)R * ldb + t * 64 + ks * 32 + kc * 8, dst + (wave * 64) * 8);
    };

    s16x8 afr[4], bfr[4];
    auto ldA = [&](int rb, int mh) {
#pragma unroll
        for (int m = 0; m < 4; ++m) {
            int R = wm * 128 + mh * 64 + m * 16 + r;
            afr[m] = *(const s16x8*)&smem[rb * BUFE + ksw * HALFA + R * 32 +
                                          ((kg ^ ((R >> 1) & 3)) * 8)];
        }
    };
    auto ldB = [&](int rb) {
#pragma unroll
        for (int n = 0; n < 4; ++n) {
            int R = wn * 64 + n * 16 + r;
            bfr[n] = *(const s16x8*)&smem[rb * BUFE + ATOT + ksw * HALFB + R * 32 +
                                          ((kg ^ ((R >> 1) & 3)) * 8)];
        }
    };
    auto preMFMA = [&]() {
        __builtin_amdgcn_s_barrier();
        asm volatile("s_waitcnt lgkmcnt(0)" ::: "memory");
        __builtin_amdgcn_sched_barrier(0);
        __builtin_amdgcn_s_setprio(1);
    };

    // prologue: stage tiles 0,1 (6 insts each)
    stageA(0, 0); stageB(0, 0); stageA(0, 1); stageB(0, 1);
    stageA(1, 0); stageB(1, 0); stageA(1, 1); stageB(1, 1);
    wait_vmcnt<6>();                        // tile 0 resident; tile 1 in flight
    __builtin_amdgcn_s_barrier();

    for (int t = 0; t < NT; ++t) {
        const int rb = t % 3;
        const bool gg = (t + 2 < NT);
        // ph0: B + A(mh0) reads; stage half of t+2 -> buf (t+2)%3 (never == rb)
        ldB(rb); ldA(rb, 0);
        if (gg) { stageA(t + 2, 0); stageB(t + 2, 0); }
        preMFMA();
#pragma unroll
        for (int m = 0; m < 4; ++m)
#pragma unroll
            for (int n = 0; n < 4; ++n)
                acc[m][n] = __builtin_amdgcn_mfma_f32_16x16x32_bf16(afr[m], bfr[n], acc[m][n], 0, 0, 0);
        __builtin_amdgcn_s_setprio(0);
        __builtin_amdgcn_s_barrier();
        // ph1: A(mh1) reads; stage other half of t+2
        ldA(rb, 1);
        if (gg) { stageA(t + 2, 1); stageB(t + 2, 1); }
        preMFMA();
#pragma unroll
        for (int m = 0; m < 4; ++m)
#pragma unroll
            for (int n = 0; n < 4; ++n)
                acc[4 + m][n] = __builtin_amdgcn_mfma_f32_16x16x32_bf16(afr[m], bfr[n], acc[4 + m][n], 0, 0, 0);
        __builtin_amdgcn_s_setprio(0);
        if (t + 1 < NT) {
            if (gg) wait_vmcnt<6>();        // tile t+1 resident (counted, never 0)
            else    wait_vmcnt<0>();
            __builtin_amdgcn_s_barrier();
        }
    }

    // ---- cross-ksw reduce via LDS (stride-68 pad), then fp32 RMW into out
    __syncthreads();                         // ring buffers dead
    float* red = (float*)smem;
    const int zone = (wm * 2 + wn) * (128 * RSTR);
    if (ksw == 1) {
#pragma unroll
        for (int mf = 0; mf < 8; ++mf) {
#pragma unroll
            for (int n = 0; n < 4; ++n) {
                int rl = (mf >> 2) * 64 + (mf & 3) * 16 + kg * 4;
                int cl = n * 16 + r;
#pragma unroll
                for (int j = 0; j < 4; ++j)
                    red[zone + (rl + j) * RSTR + cl] = acc[mf][n][j];
            }
        }
    }
    __syncthreads();
    if (ksw == 0) {
        const size_t row0 = (size_t)tm * 256 + wm * 128;
        const int col0 = tn * 128 + wn * 64;
#pragma unroll
        for (int mf = 0; mf < 8; ++mf) {
#pragma unroll
            for (int j = 0; j < 4; ++j) {
                int rl = (mf >> 2) * 64 + (mf & 3) * 16 + kg * 4 + j;
                size_t rr = row0 + rl;
#pragma unroll
                for (int n = 0; n < 4; ++n) {
                    int cl = n * 16 + r;
                    float v = acc[mf][n][j] + red[zone + rl * RSTR + cl];
                    O[rr * (size_t)ldc + col0 + cl] += v;
                }
            }
        }
    }
}

// ---------------------------------------------------------------- launch
extern "C" void kernel_launch(void* const* d_in, const int* in_sizes, int n_in,
                              void* d_out, int out_size, void* d_ws, size_t ws_size,
                              hipStream_t stream) {
    const float* x  = (const float*)d_in[0];
    const float* Wg = (const float*)d_in[1];
    const float* bg = (const float*)d_in[2];
    const float* W1 = (const float*)d_in[3];
    const float* b1 = (const float*)d_in[4];
    const float* W2 = (const float*)d_in[5];
    const float* b2 = (const float*)d_in[6];
    float* out = (float*)d_out;

    char* ws = (char*)d_ws;
    bf16* xb   = (bf16*)(ws);                          // 16 MiB  [N][D]
    bf16* W1Te = (bf16*)(ws + (16ull << 20));          // 8 MiB   [H][D] (one expert)
    bf16* W2P  = (bf16*)(ws + (24ull << 20));          // 16 MiB  [D][KPAIR] (pair)
    bf16* Hs   = (bf16*)(ws + (40ull << 20));          // 128 MiB [N][KPAIR] (pair)
    float* wts = (float*)(ws + (168ull << 20));        // 256 KiB [N][E]

    cvt_x_kernel<<<NROW * DDIM / 4 / 256, 256, 0, stream>>>(x, xb, NROW * DDIM / 4);
    gate_kernel<<<NROW / 4, 256, 0, stream>>>(x, Wg, bg, wts);
    out_init_kernel<<<NROW * DDIM / 256, 256, 0, stream>>>(wts, b2, out);

    for (int p = 0; p < 4; ++p) {
        for (int h = 0; h < 2; ++h) {
            int e = 2 * p + h;
            // W1[e]: [D][H] -> W1Te [H][D]
            transpose_cvt_kernel<<<dim3(HDIM / 128, DDIM / 64, 1), 256, 0, stream>>>(
                W1 + (size_t)e * DDIM * HDIM, W1Te, DDIM, HDIM, DDIM, 0, 0);
            // GEMM1: Hs[:, h*H ..] = w * relu(x @ W1[e] + b1[e])
            gemm1<<<512, 512, 0, stream>>>(
                xb, W1Te, Hs + (size_t)h * HDIM, b1 + (size_t)e * HDIM, wts,
                DDIM, DDIM, KPAIR, DDIM / 64, 32, 16, 2, e);
        }
        // W2 pair: [2][H][D] -> W2P [D][KPAIR]
        transpose_cvt_kernel<<<dim3(DDIM / 128, HDIM / 64, 2), 256, 0, stream>>>(
            W2 + (size_t)2 * p * HDIM * DDIM, W2P, HDIM, DDIM, KPAIR,
            (size_t)HDIM * DDIM, HDIM);
        // GEMM2 pair: out += Hs @ W2P^T   (M=8192, N=1024, K=8192)
        gemm2pair<<<256, 512, 0, stream>>>(
            Hs, W2P, out, KPAIR, KPAIR, DDIM, KPAIR / 64, 32, 8, 1);
    }
}

// Round 10
// 1310.103 us; speedup vs baseline: 1.0908x; 1.0242x over previous
//
#include <hip/hip_runtime.h>
#include <hip/hip_bf16.h>

#define DDIM 1024
#define HDIM 4096
#define NEXP 8
#define NROW 8192
#define KPAIR 8192   // 2 experts * HDIM

typedef __attribute__((ext_vector_type(8))) short s16x8;
typedef __attribute__((ext_vector_type(4))) float f32x4;

using bf16 = __hip_bfloat16;

// ---------------------------------------------------------------- helpers
__device__ __forceinline__ void gload16(const bf16* g, bf16* lds) {
    __builtin_amdgcn_global_load_lds(
        (const __attribute__((address_space(1))) unsigned int*)g,
        (__attribute__((address_space(3))) unsigned int*)lds,
        16, 0, 0);
}

template <int N>
__device__ __forceinline__ void wait_vmcnt() {
    if constexpr (N == 6)      asm volatile("s_waitcnt vmcnt(6)" ::: "memory");
    else if constexpr (N == 3) asm volatile("s_waitcnt vmcnt(3)" ::: "memory");
    else                       asm volatile("s_waitcnt vmcnt(0)" ::: "memory");
}

// ---------------------------------------------------------------- x -> bf16
__global__ void cvt_x_kernel(const float* __restrict__ x, bf16* __restrict__ xb, int total4) {
    int i = blockIdx.x * 256 + threadIdx.x;
    if (i >= total4) return;
    float4 v = ((const float4*)x)[i];
    union { bf16 b[4]; uint2 u; } p;
    p.b[0] = __float2bfloat16(v.x);
    p.b[1] = __float2bfloat16(v.y);
    p.b[2] = __float2bfloat16(v.z);
    p.b[3] = __float2bfloat16(v.w);
    ((uint2*)xb)[i] = p.u;
}

// ------------------ fp32 src [R][C] (+z*szs) -> bf16 dst [C][ldo] (+z*dzo)
// Round-8-verified fast transpose: float4 reads, LDS re-layout, s16x8
// full-line stores.
__global__ void transpose_cvt_kernel(const float* __restrict__ src, bf16* __restrict__ dst,
                                     int R, int C, int ldo, size_t szs, int dzo) {
    __shared__ float t[128][65];
    const float* s = src + (size_t)blockIdx.z * szs;
    bf16* d = dst + (size_t)blockIdx.z * dzo;
    const int r0 = blockIdx.y * 64, c0 = blockIdx.x * 128;
    const int tid = threadIdx.x;
    const int lrow = tid >> 5, lc4 = tid & 31;
#pragma unroll
    for (int i = 0; i < 8; ++i) {
        int rr = i * 8 + lrow;
        float4 v = *(const float4*)&s[(size_t)(r0 + rr) * C + c0 + lc4 * 4];
        t[lc4 * 4 + 0][rr] = v.x;
        t[lc4 * 4 + 1][rr] = v.y;
        t[lc4 * 4 + 2][rr] = v.z;
        t[lc4 * 4 + 3][rr] = v.w;
    }
    __syncthreads();
    const int oc = tid >> 3, oj = tid & 7;
#pragma unroll
    for (int i = 0; i < 4; ++i) {
        int c = oc + i * 32;
        union { bf16 b[8]; s16x8 v; } p;
#pragma unroll
        for (int q = 0; q < 8; ++q) p.b[q] = __float2bfloat16(t[c][oj * 8 + q]);
        *(s16x8*)&d[(size_t)(c0 + c) * ldo + r0 + oj * 8] = p.v;
    }
}

// ---------------------------------------------------------------- gate softmax
__global__ void gate_kernel(const float* __restrict__ x, const float* __restrict__ Wg,
                            const float* __restrict__ bg, float* __restrict__ wts) {
    int wave = threadIdx.x >> 6, lane = threadIdx.x & 63;
    int n = blockIdx.x * 4 + wave;
    const float* xr = x + (size_t)n * DDIM;
    float acc[NEXP] = {0.f, 0.f, 0.f, 0.f, 0.f, 0.f, 0.f, 0.f};
    for (int d = lane; d < DDIM; d += 64) {
        float xv = xr[d];
        const float* wr = Wg + (size_t)d * NEXP;
#pragma unroll
        for (int e = 0; e < NEXP; ++e) acc[e] += xv * wr[e];
    }
#pragma unroll
    for (int off = 32; off > 0; off >>= 1) {
#pragma unroll
        for (int e = 0; e < NEXP; ++e) acc[e] += __shfl_xor(acc[e], off, 64);
    }
    if (lane == 0) {
        float mx = -1e30f;
#pragma unroll
        for (int e = 0; e < NEXP; ++e) { acc[e] += bg[e]; mx = fmaxf(mx, acc[e]); }
        float s = 0.f;
#pragma unroll
        for (int e = 0; e < NEXP; ++e) { acc[e] = __expf(acc[e] - mx); s += acc[e]; }
        float inv = 1.0f / s;
#pragma unroll
        for (int e = 0; e < NEXP; ++e) wts[(size_t)n * NEXP + e] = acc[e] * inv;
    }
}

// ------------------------------------------- out[n,d] = sum_e w[n,e]*b2[e,d]
__global__ void out_init_kernel(const float* __restrict__ wts, const float* __restrict__ b2,
                                float* __restrict__ out) {
    size_t idx = (size_t)blockIdx.x * 256 + threadIdx.x;
    int d = (int)(idx & (DDIM - 1));
    size_t n = idx >> 10;
    const float* w = wts + n * NEXP;
    float s = 0.f;
#pragma unroll
    for (int e = 0; e < NEXP; ++e) s += w[e] * b2[(size_t)e * DDIM + d];
    out[idx] = s;
}

// ---------------------------------------------------------------- GEMM1 (8-phase, BK=64)
// BM=256 x BN=256, 8 waves 2(M)x4(N), wave-tile 128x64. Round-6/7-proven.
// dbuf-2: phase barriers are WAR-load-bearing (stage (t+2)&1 == read buf) —
// do NOT remove them here.
__global__ __launch_bounds__(512, 1) void gemm1(
    const bf16* __restrict__ A, const bf16* __restrict__ BT, bf16* __restrict__ Cout,
    const float* __restrict__ bias, const float* __restrict__ wts,
    int lda, int ldb, int ldc, int NT, int tilesM, int tilesN, int XGN, int expert) {
    constexpr int WROWS = 128;
    constexpr int HALFA = 256 * 32;
    constexpr int HALFB = 256 * 32;
    constexpr int ATOT = 2 * HALFA;
    constexpr int BUFE = ATOT + 2 * HALFB;  // 32768 elems
    __shared__ __align__(16) bf16 smem[2 * BUFE];

    const int tid = threadIdx.x;
    const int wave = tid >> 6, lane = tid & 63;
    const int wm = wave >> 2, wn = wave & 3;
    const int r = lane & 15, kg = lane >> 4;

    // ---- 2-D XCD-aware tile mapping (round-3 FETCH-verified)
    const int xcd = blockIdx.x & 7, slot = blockIdx.x >> 3;
    const int XGM = 8 / XGN;
    const int rm = tilesM / XGM, rn = tilesN / XGN;
    const int g = slot >> 5, u = slot & 31;
    const int gpr = rn >> 3;
    const int gm = (g / gpr) * 4 + (u >> 3);
    const int gn = (g % gpr) * 8 + (u & 7);
    const int tm = (xcd / XGN) * rm + gm;
    const int tn = (xcd % XGN) * rn + gn;

    const bf16* gA = A + (size_t)tm * 256 * lda;
    const bf16* gB = BT + (size_t)tn * 256 * ldb;

    f32x4 acc[8][4];
#pragma unroll
    for (int m = 0; m < 8; ++m)
#pragma unroll
        for (int n = 0; n < 4; ++n) acc[m][n] = (f32x4){0.f, 0.f, 0.f, 0.f};

    auto stageA = [&](int t, int ks) {
        bf16* dst = smem + (t & 1) * BUFE + ks * HALFA;
#pragma unroll
        for (int j = 0; j < 2; ++j) {
            int c = j * 512 + tid;
            int R = c >> 2, kc = (c & 3) ^ ((R >> 1) & 3);
            gload16(gA + (size_t)R * lda + t * 64 + ks * 32 + kc * 8,
                    dst + (j * 512 + wave * 64) * 8);
        }
    };
    auto stageB = [&](int t, int ks) {
        bf16* dst = smem + (t & 1) * BUFE + ATOT + ks * HALFB;
#pragma unroll
        for (int j = 0; j < 2; ++j) {
            int c = j * 512 + tid;
            int R = c >> 2, kc = (c & 3) ^ ((R >> 1) & 3);
            gload16(gB + (size_t)R * ldb + t * 64 + ks * 32 + kc * 8,
                    dst + (j * 512 + wave * 64) * 8);
        }
    };

    s16x8 a0[4], bb[4];
    auto ldA = [&](int buf, int ks, int mh) {
#pragma unroll
        for (int m = 0; m < 4; ++m) {
            int R = wm * WROWS + mh * 64 + m * 16 + r;
            a0[m] = *(const s16x8*)&smem[buf * BUFE + ks * HALFA + R * 32 +
                                         ((kg ^ ((R >> 1) & 3)) * 8)];
        }
    };
    auto ldB = [&](int buf, int ks) {
#pragma unroll
        for (int n = 0; n < 4; ++n) {
            int R = wn * 64 + n * 16 + r;
            bb[n] = *(const s16x8*)&smem[buf * BUFE + ATOT + ks * HALFB + R * 32 +
                                         ((kg ^ ((R >> 1) & 3)) * 8)];
        }
    };

    auto preMFMA = [&]() {
        __builtin_amdgcn_s_barrier();
        asm volatile("s_waitcnt lgkmcnt(0)" ::: "memory");
        __builtin_amdgcn_sched_barrier(0);
        __builtin_amdgcn_s_setprio(1);
    };
    auto postMFMA = [&](bool vm) {
        __builtin_amdgcn_s_setprio(0);
        if (vm) wait_vmcnt<6>();
        __builtin_amdgcn_s_barrier();
    };
    auto mfmaLo = [&]() {
#pragma unroll
        for (int m = 0; m < 4; ++m)
#pragma unroll
            for (int n = 0; n < 4; ++n)
                acc[m][n] = __builtin_amdgcn_mfma_f32_16x16x32_bf16(a0[m], bb[n], acc[m][n], 0, 0, 0);
    };
    auto mfmaHi = [&]() {
#pragma unroll
        for (int m = 0; m < 4; ++m)
#pragma unroll
            for (int n = 0; n < 4; ++n)
                acc[4 + m][n] = __builtin_amdgcn_mfma_f32_16x16x32_bf16(a0[m], bb[n], acc[4 + m][n], 0, 0, 0);
    };

    // prologue
    stageB(0, 0); stageA(0, 0); stageB(0, 1); stageA(0, 1);
    stageB(1, 0); stageA(1, 0); stageB(1, 1);   // A(1,1) staged at iter0 ph1
    wait_vmcnt<6>();
    __builtin_amdgcn_s_barrier();

    const int NI = NT / 2;
    for (int i = 0; i < NI; ++i) {
        const int t0 = 2 * i, t1 = t0 + 1;
        const bool g2 = (t0 + 2 < NT), g3 = (t1 + 2 < NT);
        ldB(0, 0); ldA(0, 0, 0); stageA(t1, 1);
        preMFMA(); mfmaLo(); postMFMA(false);
        ldA(0, 0, 1); if (g2) stageB(t0 + 2, 0);
        preMFMA(); mfmaHi(); postMFMA(false);
        ldB(0, 1); ldA(0, 1, 0); if (g2) stageA(t0 + 2, 0);
        preMFMA(); mfmaLo(); postMFMA(false);
        ldA(0, 1, 1); if (g2) stageB(t0 + 2, 1);
        preMFMA(); mfmaHi(); postMFMA(true);
        ldB(1, 0); ldA(1, 0, 0); if (g2) stageA(t0 + 2, 1);
        preMFMA(); mfmaLo(); postMFMA(false);
        ldA(1, 0, 1); if (g3) stageB(t1 + 2, 0);
        preMFMA(); mfmaHi(); postMFMA(false);
        ldB(1, 1); ldA(1, 1, 0); if (g3) stageA(t1 + 2, 0);
        preMFMA(); mfmaLo(); postMFMA(false);
        ldA(1, 1, 1); if (g3) stageB(t1 + 2, 1);
        preMFMA(); mfmaHi(); postMFMA(true);
    }

    // ---- epilogue: Hs = w * relu(acc + bias), LDS-buffered coalesced store
    bf16* hs = smem;                         // 65536 elems == 256*256
    const int col0 = tn * 256 + wn * 64;
#pragma unroll
    for (int n = 0; n < 4; ++n) {
        float bv = bias[col0 + n * 16 + r];
        int cl = wn * 64 + n * 16 + r;
#pragma unroll
        for (int mf = 0; mf < 8; ++mf) {
#pragma unroll
            for (int j = 0; j < 4; ++j) {
                int rl = wm * WROWS + (mf >> 2) * 64 + (mf & 3) * 16 + kg * 4 + j;
                float wv = wts[((size_t)tm * 256 + rl) * NEXP + expert];
                float v = acc[mf][n][j] + bv;
                v = v > 0.f ? v : 0.f;
                hs[rl * 256 + cl] = __float2bfloat16(wv * v);
            }
        }
    }
    __builtin_amdgcn_s_barrier();
    asm volatile("s_waitcnt lgkmcnt(0)" ::: "memory");
    const size_t rbase = (size_t)tm * 256;
    const int cbase = tn * 256;
#pragma unroll
    for (int i2 = 0; i2 < 16; ++i2) {
        int rl = wave * 32 + i2 * 2 + (lane >> 5);
        int c8 = (lane & 31) * 8;
        s16x8 v = *(const s16x8*)&hs[rl * 256 + c8];
        *(s16x8*)&Cout[(rbase + rl) * (size_t)ldc + cbase + c8] = v;
    }
}

// ---------------------------------------------------------------- GEMM2 (expert-pair, K=8192)
// BM=256 x BN=128, BK=64, ring-3 LDS (144 KiB). 8 waves = 2(M)x2(N)x2(Ksw).
// ROUND-10 CHANGE: ONE barrier per K-tile (ring-3 makes intra-tile barriers
// redundant: stage target (t+2)%3 never equals read buf t%3; rotation is
// guarded by tile-end vmcnt+barrier; after barrier(t) stages hit t%3 whose
// readers lgkm-drained before their MFMA before the barrier). All 12 ds_reads
// + 6 stages issued up-front; counted lgkmcnt(4) lets the A-hi reads ride
// under the first MFMA block. Waves drift within the tile -> one wave's MFMA
// overlaps its SIMD-partner's reads (T5 regime; setprio kept).
__global__ __launch_bounds__(512, 1) void gemm2pair(
    const bf16* __restrict__ A, const bf16* __restrict__ BT, float* __restrict__ O,
    int lda, int ldb, int ldc, int NT, int tilesM, int tilesN, int XGN) {
    constexpr int HALFA = 256 * 32;          // 8192 elems
    constexpr int HALFB = 128 * 32;          // 4096 elems
    constexpr int ATOT = 2 * HALFA;
    constexpr int BUFE = ATOT + 2 * HALFB;   // 24576 elems
    constexpr int RSTR = 68;                 // padded reduce stride (f32)
    __shared__ __align__(16) bf16 smem[3 * BUFE];   // 144 KiB

    const int tid = threadIdx.x;
    const int wave = tid >> 6, lane = tid & 63;
    const int ksw = wave & 1, wn = (wave >> 1) & 1, wm = wave >> 2;
    const int r = lane & 15, kg = lane >> 4;

    // ---- 2-D XCD-aware tile mapping (round-3 FETCH-verified)
    const int xcd = blockIdx.x & 7, slot = blockIdx.x >> 3;
    const int XGM = 8 / XGN;
    const int rm = tilesM / XGM, rn = tilesN / XGN;
    const int g = slot >> 5, u = slot & 31;
    const int gpr = rn >> 3;
    const int gm = (g / gpr) * 4 + (u >> 3);
    const int gn = (g % gpr) * 8 + (u & 7);
    const int tm = (xcd / XGN) * rm + gm;
    const int tn = (xcd % XGN) * rn + gn;

    const bf16* gA = A + (size_t)tm * 256 * lda;
    const bf16* gB = BT + (size_t)tn * 128 * ldb;

    f32x4 acc[8][4];
#pragma unroll
    for (int m = 0; m < 8; ++m)
#pragma unroll
        for (int n = 0; n < 4; ++n) acc[m][n] = (f32x4){0.f, 0.f, 0.f, 0.f};

    auto stageA = [&](int t, int ks) {
        bf16* dst = smem + (t % 3) * BUFE + ks * HALFA;
#pragma unroll
        for (int j = 0; j < 2; ++j) {
            int c = j * 512 + tid;
            int R = c >> 2, kc = (c & 3) ^ ((R >> 1) & 3);
            gload16(gA + (size_t)R * lda + t * 64 + ks * 32 + kc * 8,
                    dst + (j * 512 + wave * 64) * 8);
        }
    };
    auto stageB = [&](int t, int ks) {
        bf16* dst = smem + (t % 3) * BUFE + ATOT + ks * HALFB;
        int R = tid >> 2, kc = (tid & 3) ^ ((R >> 1) & 3);
        gload16(gB + (size_t)R * ldb + t * 64 + ks * 32 + kc * 8, dst + (wave * 64) * 8);
    };

    s16x8 a0[4], a1[4], bfr[4];
    auto ldA0 = [&](int rb) {
#pragma unroll
        for (int m = 0; m < 4; ++m) {
            int R = wm * 128 + m * 16 + r;
            a0[m] = *(const s16x8*)&smem[rb * BUFE + ksw * HALFA + R * 32 +
                                         ((kg ^ ((R >> 1) & 3)) * 8)];
        }
    };
    auto ldA1 = [&](int rb) {
#pragma unroll
        for (int m = 0; m < 4; ++m) {
            int R = wm * 128 + 64 + m * 16 + r;
            a1[m] = *(const s16x8*)&smem[rb * BUFE + ksw * HALFA + R * 32 +
                                         ((kg ^ ((R >> 1) & 3)) * 8)];
        }
    };
    auto ldB = [&](int rb) {
#pragma unroll
        for (int n = 0; n < 4; ++n) {
            int R = wn * 64 + n * 16 + r;
            bfr[n] = *(const s16x8*)&smem[rb * BUFE + ATOT + ksw * HALFB + R * 32 +
                                          ((kg ^ ((R >> 1) & 3)) * 8)];
        }
    };

    // prologue: stage tiles 0,1 (6 insts each)
    stageA(0, 0); stageB(0, 0); stageA(0, 1); stageB(0, 1);
    stageA(1, 0); stageB(1, 0); stageA(1, 1); stageB(1, 1);
    wait_vmcnt<6>();                        // tile 0 resident; tile 1 in flight
    __builtin_amdgcn_s_barrier();

    for (int t = 0; t < NT; ++t) {
        const int rb = t % 3;
        const bool gg = (t + 2 < NT);
        // issue everything up-front: 8 reads (B + A-lo), 3 stages, 4 reads
        // (A-hi), 3 stages
        ldB(rb); ldA0(rb);
        if (gg) { stageA(t + 2, 0); stageB(t + 2, 0); }
        ldA1(rb);
        if (gg) { stageA(t + 2, 1); stageB(t + 2, 1); }
        // first 8 ds_reads resident (4 A-hi still in flight under MFMA)
        asm volatile("s_waitcnt lgkmcnt(4)" ::: "memory");
        __builtin_amdgcn_sched_barrier(0);
        __builtin_amdgcn_s_setprio(1);
#pragma unroll
        for (int m = 0; m < 4; ++m)
#pragma unroll
            for (int n = 0; n < 4; ++n)
                acc[m][n] = __builtin_amdgcn_mfma_f32_16x16x32_bf16(a0[m], bfr[n], acc[m][n], 0, 0, 0);
        __builtin_amdgcn_s_setprio(0);
        asm volatile("s_waitcnt lgkmcnt(0)" ::: "memory");
        __builtin_amdgcn_sched_barrier(0);
        __builtin_amdgcn_s_setprio(1);
#pragma unroll
        for (int m = 0; m < 4; ++m)
#pragma unroll
            for (int n = 0; n < 4; ++n)
                acc[4 + m][n] = __builtin_amdgcn_mfma_f32_16x16x32_bf16(a1[m], bfr[n], acc[4 + m][n], 0, 0, 0);
        __builtin_amdgcn_s_setprio(0);
        // single tile-boundary sync: tile t+1 resident (counted, never 0 mid-loop)
        if (t + 1 < NT) {
            if (gg) wait_vmcnt<6>();
            else    wait_vmcnt<0>();
            __builtin_amdgcn_s_barrier();
        }
    }

    // ---- cross-ksw reduce via LDS (stride-68 pad, 0-conflict), fp32 RMW out
    __syncthreads();                         // ring buffers dead
    float* red = (float*)smem;
    const int zone = (wm * 2 + wn) * (128 * RSTR);
    if (ksw == 1) {
#pragma unroll
        for (int mf = 0; mf < 8; ++mf) {
#pragma unroll
            for (int n = 0; n < 4; ++n) {
                int rl = (mf >> 2) * 64 + (mf & 3) * 16 + kg * 4;
                int cl = n * 16 + r;
#pragma unroll
                for (int j = 0; j < 4; ++j)
                    red[zone + (rl + j) * RSTR + cl] = acc[mf][n][j];
            }
        }
    }
    __syncthreads();
    if (ksw == 0) {
        const size_t row0 = (size_t)tm * 256 + wm * 128;
        const int col0 = tn * 128 + wn * 64;
#pragma unroll
        for (int mf = 0; mf < 8; ++mf) {
#pragma unroll
            for (int j = 0; j < 4; ++j) {
                int rl = (mf >> 2) * 64 + (mf & 3) * 16 + kg * 4 + j;
                size_t rr = row0 + rl;
#pragma unroll
                for (int n = 0; n < 4; ++n) {
                    int cl = n * 16 + r;
                    float v = acc[mf][n][j] + red[zone + rl * RSTR + cl];
                    O[rr * (size_t)ldc + col0 + cl] += v;
                }
            }
        }
    }
}

// ---------------------------------------------------------------- launch
extern "C" void kernel_launch(void* const* d_in, const int* in_sizes, int n_in,
                              void* d_out, int out_size, void* d_ws, size_t ws_size,
                              hipStream_t stream) {
    const float* x  = (const float*)d_in[0];
    const float* Wg = (const float*)d_in[1];
    const float* bg = (const float*)d_in[2];
    const float* W1 = (const float*)d_in[3];
    const float* b1 = (const float*)d_in[4];
    const float* W2 = (const float*)d_in[5];
    const float* b2 = (const float*)d_in[6];
    float* out = (float*)d_out;

    char* ws = (char*)d_ws;
    bf16* xb   = (bf16*)(ws);                          // 16 MiB  [N][D]
    bf16* W1Te = (bf16*)(ws + (16ull << 20));          // 8 MiB   [H][D] (one expert)
    bf16* W2P  = (bf16*)(ws + (24ull << 20));          // 16 MiB  [D][KPAIR] (pair)
    bf16* Hs   = (bf16*)(ws + (40ull << 20));          // 128 MiB [N][KPAIR] (pair)
    float* wts = (float*)(ws + (168ull << 20));        // 256 KiB [N][E]

    cvt_x_kernel<<<NROW * DDIM / 4 / 256, 256, 0, stream>>>(x, xb, NROW * DDIM / 4);
    gate_kernel<<<NROW / 4, 256, 0, stream>>>(x, Wg, bg, wts);
    out_init_kernel<<<NROW * DDIM / 256, 256, 0, stream>>>(wts, b2, out);

    for (int p = 0; p < 4; ++p) {
        for (int h = 0; h < 2; ++h) {
            int e = 2 * p + h;
            // W1[e]: [D][H] -> W1Te [H][D]
            transpose_cvt_kernel<<<dim3(HDIM / 128, DDIM / 64, 1), 256, 0, stream>>>(
                W1 + (size_t)e * DDIM * HDIM, W1Te, DDIM, HDIM, DDIM, 0, 0);
            // GEMM1: Hs[:, h*H ..] = w * relu(x @ W1[e] + b1[e])
            gemm1<<<512, 512, 0, stream>>>(
                xb, W1Te, Hs + (size_t)h * HDIM, b1 + (size_t)e * HDIM, wts,
                DDIM, DDIM, KPAIR, DDIM / 64, 32, 16, 2, e);
        }
        // W2 pair: [2][H][D] -> W2P [D][KPAIR]
        transpose_cvt_kernel<<<dim3(DDIM / 128, HDIM / 64, 2), 256, 0, stream>>>(
            W2 + (size_t)2 * p * HDIM * DDIM, W2P, HDIM, DDIM, KPAIR,
            (size_t)HDIM * DDIM, HDIM);
        // GEMM2 pair: out += Hs @ W2P^T   (M=8192, N=1024, K=8192)
        gemm2pair<<<256, 512, 0, stream>>>(
            Hs, W2P, out, KPAIR, KPAIR, DDIM, KPAIR / 64, 32, 8, 1);
    }
}

// Round 11
// 1296.753 us; speedup vs baseline: 1.1021x; 1.0103x over previous
//
#include <hip/hip_runtime.h>
#include <hip/hip_bf16.h>

#define DDIM 1024
#define HDIM 4096
#define NEXP 8
#define NROW 8192
#define KPAIR 8192   // 2 experts * HDIM

typedef __attribute__((ext_vector_type(8))) short s16x8;
typedef __attribute__((ext_vector_type(4))) float f32x4;

using bf16 = __hip_bfloat16;

// ---------------------------------------------------------------- helpers
__device__ __forceinline__ void gload16(const bf16* g, bf16* lds) {
    __builtin_amdgcn_global_load_lds(
        (const __attribute__((address_space(1))) unsigned int*)g,
        (__attribute__((address_space(3))) unsigned int*)lds,
        16, 0, 0);
}

template <int N>
__device__ __forceinline__ void wait_vmcnt() {
    if constexpr (N == 6)      asm volatile("s_waitcnt vmcnt(6)" ::: "memory");
    else if constexpr (N == 3) asm volatile("s_waitcnt vmcnt(3)" ::: "memory");
    else                       asm volatile("s_waitcnt vmcnt(0)" ::: "memory");
}

// ---------------------------------------- fused x->bf16 convert + gate softmax
// One wave per row: converts the row to bf16 (coalesced float4 -> uint2) and
// accumulates the 8-expert gate dot in the same pass (x read ONCE).
__global__ void cvtgate_kernel(const float* __restrict__ x, const float* __restrict__ Wg,
                               const float* __restrict__ bg, bf16* __restrict__ xb,
                               float* __restrict__ wts) {
    int wave = threadIdx.x >> 6, lane = threadIdx.x & 63;
    int n = blockIdx.x * 4 + wave;
    const float* xr = x + (size_t)n * DDIM;
    bf16* xbr = xb + (size_t)n * DDIM;
    float acc[NEXP] = {0.f, 0.f, 0.f, 0.f, 0.f, 0.f, 0.f, 0.f};
#pragma unroll
    for (int j = 0; j < 4; ++j) {
        int d0 = j * 256 + lane * 4;
        float4 v = *(const float4*)&xr[d0];
        union { bf16 b[4]; uint2 u; } pk;
        pk.b[0] = __float2bfloat16(v.x);
        pk.b[1] = __float2bfloat16(v.y);
        pk.b[2] = __float2bfloat16(v.z);
        pk.b[3] = __float2bfloat16(v.w);
        *(uint2*)&xbr[d0] = pk.u;
        const float* w0 = Wg + (size_t)d0 * NEXP;
#pragma unroll
        for (int e = 0; e < NEXP; ++e)
            acc[e] += v.x * w0[e] + v.y * w0[NEXP + e] + v.z * w0[2 * NEXP + e] +
                      v.w * w0[3 * NEXP + e];
    }
#pragma unroll
    for (int off = 32; off > 0; off >>= 1) {
#pragma unroll
        for (int e = 0; e < NEXP; ++e) acc[e] += __shfl_xor(acc[e], off, 64);
    }
    if (lane == 0) {
        float mx = -1e30f;
#pragma unroll
        for (int e = 0; e < NEXP; ++e) { acc[e] += bg[e]; mx = fmaxf(mx, acc[e]); }
        float s = 0.f;
#pragma unroll
        for (int e = 0; e < NEXP; ++e) { acc[e] = __expf(acc[e] - mx); s += acc[e]; }
        float inv = 1.0f / s;
#pragma unroll
        for (int e = 0; e < NEXP; ++e) wts[(size_t)n * NEXP + e] = acc[e] * inv;
    }
}

// ------------------ fp32 src [R][C] (+z*szs) -> bf16 dst [C][ldo] (+z*dzo)
// Round-8-verified fast transpose: float4 reads, LDS re-layout, s16x8
// full-line stores.
__global__ void transpose_cvt_kernel(const float* __restrict__ src, bf16* __restrict__ dst,
                                     int R, int C, int ldo, size_t szs, int dzo) {
    __shared__ float t[128][65];
    const float* s = src + (size_t)blockIdx.z * szs;
    bf16* d = dst + (size_t)blockIdx.z * dzo;
    const int r0 = blockIdx.y * 64, c0 = blockIdx.x * 128;
    const int tid = threadIdx.x;
    const int lrow = tid >> 5, lc4 = tid & 31;
#pragma unroll
    for (int i = 0; i < 8; ++i) {
        int rr = i * 8 + lrow;
        float4 v = *(const float4*)&s[(size_t)(r0 + rr) * C + c0 + lc4 * 4];
        t[lc4 * 4 + 0][rr] = v.x;
        t[lc4 * 4 + 1][rr] = v.y;
        t[lc4 * 4 + 2][rr] = v.z;
        t[lc4 * 4 + 3][rr] = v.w;
    }
    __syncthreads();
    const int oc = tid >> 3, oj = tid & 7;
#pragma unroll
    for (int i = 0; i < 4; ++i) {
        int c = oc + i * 32;
        union { bf16 b[8]; s16x8 v; } p;
#pragma unroll
        for (int q = 0; q < 8; ++q) p.b[q] = __float2bfloat16(t[c][oj * 8 + q]);
        *(s16x8*)&d[(size_t)(c0 + c) * ldo + r0 + oj * 8] = p.v;
    }
}

// ------------------------------------------- out[n,d] = sum_e w[n,e]*b2[e,d]
__global__ void out_init_kernel(const float* __restrict__ wts, const float* __restrict__ b2,
                                float* __restrict__ out) {
    size_t idx = (size_t)blockIdx.x * 256 + threadIdx.x;
    int d = (int)(idx & (DDIM - 1));
    size_t n = idx >> 10;
    const float* w = wts + n * NEXP;
    float s = 0.f;
#pragma unroll
    for (int e = 0; e < NEXP; ++e) s += w[e] * b2[(size_t)e * DDIM + d];
    out[idx] = s;
}

// ---------------------------------------------------------------- GEMM1 (8-phase, BK=64)
// BM=256 x BN=256, 8 waves 2(M)x4(N), wave-tile 128x64. Round-6/7-proven.
// ROUND-11: one dispatch covers BOTH experts of the pair (grid 1024:
// eh = blockIdx>>9 selects expert-half; bx = blockIdx&511 keeps the
// FETCH-verified XCD mapping). dbuf-2 phase barriers are WAR-load-bearing.
__global__ __launch_bounds__(512, 1) void gemm1(
    const bf16* __restrict__ A, const bf16* __restrict__ BTp, bf16* __restrict__ Hsb,
    const float* __restrict__ b1p, const float* __restrict__ wts,
    int lda, int ldb, int ldc, int NT, int tilesM, int tilesN, int XGN, int e0) {
    constexpr int WROWS = 128;
    constexpr int HALFA = 256 * 32;
    constexpr int HALFB = 256 * 32;
    constexpr int ATOT = 2 * HALFA;
    constexpr int BUFE = ATOT + 2 * HALFB;  // 32768 elems
    __shared__ __align__(16) bf16 smem[2 * BUFE];

    const int tid = threadIdx.x;
    const int wave = tid >> 6, lane = tid & 63;
    const int wm = wave >> 2, wn = wave & 3;
    const int r = lane & 15, kg = lane >> 4;

    // expert half of the pair
    const int eh = blockIdx.x >> 9;
    const int bx = blockIdx.x & 511;
    const bf16* BT = BTp + (size_t)eh * HDIM * DDIM;
    bf16* Cout = Hsb + (size_t)eh * HDIM;
    const float* bias = b1p + (size_t)eh * HDIM;
    const int expert = e0 + eh;

    // ---- 2-D XCD-aware tile mapping (round-3 FETCH-verified)
    const int xcd = bx & 7, slot = bx >> 3;
    const int XGM = 8 / XGN;
    const int rm = tilesM / XGM, rn = tilesN / XGN;
    const int g = slot >> 5, u = slot & 31;
    const int gpr = rn >> 3;
    const int gm = (g / gpr) * 4 + (u >> 3);
    const int gn = (g % gpr) * 8 + (u & 7);
    const int tm = (xcd / XGN) * rm + gm;
    const int tn = (xcd % XGN) * rn + gn;

    const bf16* gA = A + (size_t)tm * 256 * lda;
    const bf16* gB = BT + (size_t)tn * 256 * ldb;

    f32x4 acc[8][4];
#pragma unroll
    for (int m = 0; m < 8; ++m)
#pragma unroll
        for (int n = 0; n < 4; ++n) acc[m][n] = (f32x4){0.f, 0.f, 0.f, 0.f};

    auto stageA = [&](int t, int ks) {
        bf16* dst = smem + (t & 1) * BUFE + ks * HALFA;
#pragma unroll
        for (int j = 0; j < 2; ++j) {
            int c = j * 512 + tid;
            int R = c >> 2, kc = (c & 3) ^ ((R >> 1) & 3);
            gload16(gA + (size_t)R * lda + t * 64 + ks * 32 + kc * 8,
                    dst + (j * 512 + wave * 64) * 8);
        }
    };
    auto stageB = [&](int t, int ks) {
        bf16* dst = smem + (t & 1) * BUFE + ATOT + ks * HALFB;
#pragma unroll
        for (int j = 0; j < 2; ++j) {
            int c = j * 512 + tid;
            int R = c >> 2, kc = (c & 3) ^ ((R >> 1) & 3);
            gload16(gB + (size_t)R * ldb + t * 64 + ks * 32 + kc * 8,
                    dst + (j * 512 + wave * 64) * 8);
        }
    };

    s16x8 a0[4], bb[4];
    auto ldA = [&](int buf, int ks, int mh) {
#pragma unroll
        for (int m = 0; m < 4; ++m) {
            int R = wm * WROWS + mh * 64 + m * 16 + r;
            a0[m] = *(const s16x8*)&smem[buf * BUFE + ks * HALFA + R * 32 +
                                         ((kg ^ ((R >> 1) & 3)) * 8)];
        }
    };
    auto ldB = [&](int buf, int ks) {
#pragma unroll
        for (int n = 0; n < 4; ++n) {
            int R = wn * 64 + n * 16 + r;
            bb[n] = *(const s16x8*)&smem[buf * BUFE + ATOT + ks * HALFB + R * 32 +
                                         ((kg ^ ((R >> 1) & 3)) * 8)];
        }
    };

    auto preMFMA = [&]() {
        __builtin_amdgcn_s_barrier();
        asm volatile("s_waitcnt lgkmcnt(0)" ::: "memory");
        __builtin_amdgcn_sched_barrier(0);
        __builtin_amdgcn_s_setprio(1);
    };
    auto postMFMA = [&](bool vm) {
        __builtin_amdgcn_s_setprio(0);
        if (vm) wait_vmcnt<6>();
        __builtin_amdgcn_s_barrier();
    };
    auto mfmaLo = [&]() {
#pragma unroll
        for (int m = 0; m < 4; ++m)
#pragma unroll
            for (int n = 0; n < 4; ++n)
                acc[m][n] = __builtin_amdgcn_mfma_f32_16x16x32_bf16(a0[m], bb[n], acc[m][n], 0, 0, 0);
    };
    auto mfmaHi = [&]() {
#pragma unroll
        for (int m = 0; m < 4; ++m)
#pragma unroll
            for (int n = 0; n < 4; ++n)
                acc[4 + m][n] = __builtin_amdgcn_mfma_f32_16x16x32_bf16(a0[m], bb[n], acc[4 + m][n], 0, 0, 0);
    };

    // prologue
    stageB(0, 0); stageA(0, 0); stageB(0, 1); stageA(0, 1);
    stageB(1, 0); stageA(1, 0); stageB(1, 1);   // A(1,1) staged at iter0 ph1
    wait_vmcnt<6>();
    __builtin_amdgcn_s_barrier();

    const int NI = NT / 2;
    for (int i = 0; i < NI; ++i) {
        const int t0 = 2 * i, t1 = t0 + 1;
        const bool g2 = (t0 + 2 < NT), g3 = (t1 + 2 < NT);
        ldB(0, 0); ldA(0, 0, 0); stageA(t1, 1);
        preMFMA(); mfmaLo(); postMFMA(false);
        ldA(0, 0, 1); if (g2) stageB(t0 + 2, 0);
        preMFMA(); mfmaHi(); postMFMA(false);
        ldB(0, 1); ldA(0, 1, 0); if (g2) stageA(t0 + 2, 0);
        preMFMA(); mfmaLo(); postMFMA(false);
        ldA(0, 1, 1); if (g2) stageB(t0 + 2, 1);
        preMFMA(); mfmaHi(); postMFMA(true);
        ldB(1, 0); ldA(1, 0, 0); if (g2) stageA(t0 + 2, 1);
        preMFMA(); mfmaLo(); postMFMA(false);
        ldA(1, 0, 1); if (g3) stageB(t1 + 2, 0);
        preMFMA(); mfmaHi(); postMFMA(false);
        ldB(1, 1); ldA(1, 1, 0); if (g3) stageA(t1 + 2, 0);
        preMFMA(); mfmaLo(); postMFMA(false);
        ldA(1, 1, 1); if (g3) stageB(t1 + 2, 1);
        preMFMA(); mfmaHi(); postMFMA(true);
    }

    // ---- epilogue: Hs = w * relu(acc + bias), LDS-buffered coalesced store
    bf16* hs = smem;                         // 65536 elems == 256*256
    const int col0 = tn * 256 + wn * 64;
#pragma unroll
    for (int n = 0; n < 4; ++n) {
        float bv = bias[col0 + n * 16 + r];
        int cl = wn * 64 + n * 16 + r;
#pragma unroll
        for (int mf = 0; mf < 8; ++mf) {
#pragma unroll
            for (int j = 0; j < 4; ++j) {
                int rl = wm * WROWS + (mf >> 2) * 64 + (mf & 3) * 16 + kg * 4 + j;
                float wv = wts[((size_t)tm * 256 + rl) * NEXP + expert];
                float v = acc[mf][n][j] + bv;
                v = v > 0.f ? v : 0.f;
                hs[rl * 256 + cl] = __float2bfloat16(wv * v);
            }
        }
    }
    __builtin_amdgcn_s_barrier();
    asm volatile("s_waitcnt lgkmcnt(0)" ::: "memory");
    const size_t rbase = (size_t)tm * 256;
    const int cbase = tn * 256;
#pragma unroll
    for (int i2 = 0; i2 < 16; ++i2) {
        int rl = wave * 32 + i2 * 2 + (lane >> 5);
        int c8 = (lane & 31) * 8;
        s16x8 v = *(const s16x8*)&hs[rl * 256 + c8];
        *(s16x8*)&Cout[(rbase + rl) * (size_t)ldc + cbase + c8] = v;
    }
}

// ---------------------------------------------------------------- GEMM2 (expert-pair, K=8192)
// BM=256 x BN=128, BK=64, ring-3 LDS (144 KiB). 8 waves = 2(M)x2(N)x2(Ksw).
// Round-10 structure (best measured): one barrier per K-tile, all reads+
// stages issued up-front, counted lgkmcnt(4)/vmcnt(6), setprio around MFMA.
__global__ __launch_bounds__(512, 1) void gemm2pair(
    const bf16* __restrict__ A, const bf16* __restrict__ BT, float* __restrict__ O,
    int lda, int ldb, int ldc, int NT, int tilesM, int tilesN, int XGN) {
    constexpr int HALFA = 256 * 32;          // 8192 elems
    constexpr int HALFB = 128 * 32;          // 4096 elems
    constexpr int ATOT = 2 * HALFA;
    constexpr int BUFE = ATOT + 2 * HALFB;   // 24576 elems
    constexpr int RSTR = 68;                 // padded reduce stride (f32)
    __shared__ __align__(16) bf16 smem[3 * BUFE];   // 144 KiB

    const int tid = threadIdx.x;
    const int wave = tid >> 6, lane = tid & 63;
    const int ksw = wave & 1, wn = (wave >> 1) & 1, wm = wave >> 2;
    const int r = lane & 15, kg = lane >> 4;

    // ---- 2-D XCD-aware tile mapping (round-3 FETCH-verified)
    const int xcd = blockIdx.x & 7, slot = blockIdx.x >> 3;
    const int XGM = 8 / XGN;
    const int rm = tilesM / XGM, rn = tilesN / XGN;
    const int g = slot >> 5, u = slot & 31;
    const int gpr = rn >> 3;
    const int gm = (g / gpr) * 4 + (u >> 3);
    const int gn = (g % gpr) * 8 + (u & 7);
    const int tm = (xcd / XGN) * rm + gm;
    const int tn = (xcd % XGN) * rn + gn;

    const bf16* gA = A + (size_t)tm * 256 * lda;
    const bf16* gB = BT + (size_t)tn * 128 * ldb;

    f32x4 acc[8][4];
#pragma unroll
    for (int m = 0; m < 8; ++m)
#pragma unroll
        for (int n = 0; n < 4; ++n) acc[m][n] = (f32x4){0.f, 0.f, 0.f, 0.f};

    auto stageA = [&](int t, int ks) {
        bf16* dst = smem + (t % 3) * BUFE + ks * HALFA;
#pragma unroll
        for (int j = 0; j < 2; ++j) {
            int c = j * 512 + tid;
            int R = c >> 2, kc = (c & 3) ^ ((R >> 1) & 3);
            gload16(gA + (size_t)R * lda + t * 64 + ks * 32 + kc * 8,
                    dst + (j * 512 + wave * 64) * 8);
        }
    };
    auto stageB = [&](int t, int ks) {
        bf16* dst = smem + (t % 3) * BUFE + ATOT + ks * HALFB;
        int R = tid >> 2, kc = (tid & 3) ^ ((R >> 1) & 3);
        gload16(gB + (size_t)R * ldb + t * 64 + ks * 32 + kc * 8, dst + (wave * 64) * 8);
    };

    s16x8 a0[4], a1[4], bfr[4];
    auto ldA0 = [&](int rb) {
#pragma unroll
        for (int m = 0; m < 4; ++m) {
            int R = wm * 128 + m * 16 + r;
            a0[m] = *(const s16x8*)&smem[rb * BUFE + ksw * HALFA + R * 32 +
                                         ((kg ^ ((R >> 1) & 3)) * 8)];
        }
    };
    auto ldA1 = [&](int rb) {
#pragma unroll
        for (int m = 0; m < 4; ++m) {
            int R = wm * 128 + 64 + m * 16 + r;
            a1[m] = *(const s16x8*)&smem[rb * BUFE + ksw * HALFA + R * 32 +
                                         ((kg ^ ((R >> 1) & 3)) * 8)];
        }
    };
    auto ldB = [&](int rb) {
#pragma unroll
        for (int n = 0; n < 4; ++n) {
            int R = wn * 64 + n * 16 + r;
            bfr[n] = *(const s16x8*)&smem[rb * BUFE + ATOT + ksw * HALFB + R * 32 +
                                          ((kg ^ ((R >> 1) & 3)) * 8)];
        }
    };

    // prologue: stage tiles 0,1 (6 insts each)
    stageA(0, 0); stageB(0, 0); stageA(0, 1); stageB(0, 1);
    stageA(1, 0); stageB(1, 0); stageA(1, 1); stageB(1, 1);
    wait_vmcnt<6>();                        // tile 0 resident; tile 1 in flight
    __builtin_amdgcn_s_barrier();

    for (int t = 0; t < NT; ++t) {
        const int rb = t % 3;
        const bool gg = (t + 2 < NT);
        ldB(rb); ldA0(rb);
        if (gg) { stageA(t + 2, 0); stageB(t + 2, 0); }
        ldA1(rb);
        if (gg) { stageA(t + 2, 1); stageB(t + 2, 1); }
        asm volatile("s_waitcnt lgkmcnt(4)" ::: "memory");
        __builtin_amdgcn_sched_barrier(0);
        __builtin_amdgcn_s_setprio(1);
#pragma unroll
        for (int m = 0; m < 4; ++m)
#pragma unroll
            for (int n = 0; n < 4; ++n)
                acc[m][n] = __builtin_amdgcn_mfma_f32_16x16x32_bf16(a0[m], bfr[n], acc[m][n], 0, 0, 0);
        __builtin_amdgcn_s_setprio(0);
        asm volatile("s_waitcnt lgkmcnt(0)" ::: "memory");
        __builtin_amdgcn_sched_barrier(0);
        __builtin_amdgcn_s_setprio(1);
#pragma unroll
        for (int m = 0; m < 4; ++m)
#pragma unroll
            for (int n = 0; n < 4; ++n)
                acc[4 + m][n] = __builtin_amdgcn_mfma_f32_16x16x32_bf16(a1[m], bfr[n], acc[4 + m][n], 0, 0, 0);
        __builtin_amdgcn_s_setprio(0);
        if (t + 1 < NT) {
            if (gg) wait_vmcnt<6>();
            else    wait_vmcnt<0>();
            __builtin_amdgcn_s_barrier();
        }
    }

    // ---- cross-ksw reduce via LDS (stride-68 pad, 0-conflict), fp32 RMW out
    __syncthreads();                         // ring buffers dead
    float* red = (float*)smem;
    const int zone = (wm * 2 + wn) * (128 * RSTR);
    if (ksw == 1) {
#pragma unroll
        for (int mf = 0; mf < 8; ++mf) {
#pragma unroll
            for (int n = 0; n < 4; ++n) {
                int rl = (mf >> 2) * 64 + (mf & 3) * 16 + kg * 4;
                int cl = n * 16 + r;
#pragma unroll
                for (int j = 0; j < 4; ++j)
                    red[zone + (rl + j) * RSTR + cl] = acc[mf][n][j];
            }
        }
    }
    __syncthreads();
    if (ksw == 0) {
        const size_t row0 = (size_t)tm * 256 + wm * 128;
        const int col0 = tn * 128 + wn * 64;
#pragma unroll
        for (int mf = 0; mf < 8; ++mf) {
#pragma unroll
            for (int j = 0; j < 4; ++j) {
                int rl = (mf >> 2) * 64 + (mf & 3) * 16 + kg * 4 + j;
                size_t rr = row0 + rl;
#pragma unroll
                for (int n = 0; n < 4; ++n) {
                    int cl = n * 16 + r;
                    float v = acc[mf][n][j] + red[zone + rl * RSTR + cl];
                    O[rr * (size_t)ldc + col0 + cl] += v;
                }
            }
        }
    }
}

// ---------------------------------------------------------------- launch
extern "C" void kernel_launch(void* const* d_in, const int* in_sizes, int n_in,
                              void* d_out, int out_size, void* d_ws, size_t ws_size,
                              hipStream_t stream) {
    const float* x  = (const float*)d_in[0];
    const float* Wg = (const float*)d_in[1];
    const float* bg = (const float*)d_in[2];
    const float* W1 = (const float*)d_in[3];
    const float* b1 = (const float*)d_in[4];
    const float* W2 = (const float*)d_in[5];
    const float* b2 = (const float*)d_in[6];
    float* out = (float*)d_out;

    char* ws = (char*)d_ws;
    bf16* xb   = (bf16*)(ws);                          // 16 MiB  [N][D]
    bf16* W1P  = (bf16*)(ws + (16ull << 20));          // 16 MiB  [2][H][D] (pair)
    bf16* W2P  = (bf16*)(ws + (32ull << 20));          // 16 MiB  [D][KPAIR] (pair)
    bf16* Hs   = (bf16*)(ws + (48ull << 20));          // 128 MiB [N][KPAIR] (pair)
    float* wts = (float*)(ws + (176ull << 20));        // 256 KiB [N][E]

    cvtgate_kernel<<<NROW / 4, 256, 0, stream>>>(x, Wg, bg, xb, wts);
    out_init_kernel<<<NROW * DDIM / 256, 256, 0, stream>>>(wts, b2, out);

    for (int p = 0; p < 4; ++p) {
        // W1 pair: [2][D][H] -> W1P [2][H][D]
        transpose_cvt_kernel<<<dim3(HDIM / 128, DDIM / 64, 2), 256, 0, stream>>>(
            W1 + (size_t)2 * p * DDIM * HDIM, W1P, DDIM, HDIM, DDIM,
            (size_t)DDIM * HDIM, HDIM * DDIM);
        // GEMM1 (both experts): Hs[:, eh*H ..] = w * relu(x @ W1[e] + b1[e])
        gemm1<<<1024, 512, 0, stream>>>(
            xb, W1P, Hs, b1 + (size_t)2 * p * HDIM, wts,
            DDIM, DDIM, KPAIR, DDIM / 64, 32, 16, 2, 2 * p);
        // W2 pair: [2][H][D] -> W2P [D][KPAIR]
        transpose_cvt_kernel<<<dim3(DDIM / 128, HDIM / 64, 2), 256, 0, stream>>>(
            W2 + (size_t)2 * p * HDIM * DDIM, W2P, HDIM, DDIM, KPAIR,
            (size_t)HDIM * DDIM, HDIM);
        // GEMM2 pair: out += Hs @ W2P^T   (M=8192, N=1024, K=8192)
        gemm2pair<<<256, 512, 0, stream>>>(
            Hs, W2P, out, KPAIR, KPAIR, DDIM, KPAIR / 64, 32, 8, 1);
    }
}